// Round 3
// baseline (90.728 us; speedup 1.0000x reference)
//
#include <hip/hip_runtime.h>
#include <hip/hip_cooperative_groups.h>

namespace cg = cooperative_groups;

#define T_HOR 5
#define G0    40                 // first sync after 40 iterations (n* estimated 41-45)
#define NT    15                 // then 15 groups of 4 -> cap 40 + 60 = 100 = LQR_ITER
#define EPSC  0.01f

typedef float f2 __attribute__((ext_vector_type(2)));

// One LQR sweep for one batch element. The two independent 2-state subsystems
// ride in lanes .x/.y of packed f32x2 (-> v_pk_fma_f32 on gfx950).
// Returns max |du| over all controls/timesteps.
__device__ __forceinline__ float iter_once(
    const float (&c0)[T_HOR], const float (&c1)[T_HOR],
    const float (&gp)[T_HOR], const float (&hp)[T_HOR],
    f2 xip, f2 xiv, f2 pcp, f2 pcv,
    f2 (&ua)[T_HOR], f2 (&ub)[T_HOR])
{
    // rollout
    f2 xp[T_HOR], xv[T_HOR];
    xp[0] = xip; xv[0] = xiv;
    #pragma unroll
    for (int t = 0; t < T_HOR-1; ++t) {
        xp[t+1] = xp[t] + 0.1f*xv[t];
        xv[t+1] = 0.75f*xv[t] + 0.5f*(ua[t]-ub[t]);
    }

    // backward affine pass (quadratic part is compile-time constant)
    f2 ka[T_HOR], kb[T_HOR];
    f2 vp = {0.f, 0.f}, vv = {0.f, 0.f};
    #pragma unroll
    for (int t = T_HOR-1; t >= 0; --t) {
        f2 qa = 0.01f + 0.1f*ua[t] + 0.5f*vv;
        f2 qb = 0.01f + 0.1f*ub[t] - 0.5f*vv;
        ka[t] = -(c0[t]*qa + c1[t]*qb);
        kb[t] = -(c1[t]*qa + c0[t]*qb);
        f2 qxp = pcp + xp[t] + vp;
        f2 qxv = pcv + 0.1f*xv[t] + 0.1f*vp + 0.75f*vv;
        f2 dq = qa - qb;
        vp = qxp - gp[t]*dq;
        vv = qxv - hp[t]*dq;
    }

    // forward pass with clip; two per-lane delta accumulators (shorter chain)
    f2 dmax = {0.f, 0.f};
    f2 dp = {0.f, 0.f}, dv = {0.f, 0.f};
    #pragma unroll
    for (int t = 0; t < T_HOR; ++t) {
        f2 phi = gp[t]*dp + hp[t]*dv;
        f2 ra = ua[t] + (ka[t] - phi);
        f2 rb = ub[t] + (kb[t] + phi);
        f2 na, nb;
        na.x = __builtin_amdgcn_fmed3f(ra.x, 0.f, 1.f);
        na.y = __builtin_amdgcn_fmed3f(ra.y, 0.f, 1.f);
        nb.x = __builtin_amdgcn_fmed3f(rb.x, 0.f, 1.f);
        nb.y = __builtin_amdgcn_fmed3f(rb.y, 0.f, 1.f);
        f2 dua = na - ua[t], dub = nb - ub[t];
        dmax.x = fmaxf(dmax.x, fmaxf(fabsf(dua.x), fabsf(dub.x)));
        dmax.y = fmaxf(dmax.y, fmaxf(fabsf(dua.y), fabsf(dub.y)));
        f2 ndp = dp + 0.1f*dv;
        f2 ndv = 0.75f*dv + 0.5f*(dua - dub);
        dp = ndp; dv = ndv;
        ua[t] = na; ub[t] = nb;
    }
    return fmaxf(dmax.x, dmax.y);
}

__global__ __launch_bounds__(256, 1)
void mpc_iter_kernel(const float4* __restrict__ x_init,
                     const float4* __restrict__ xd,
                     float4* __restrict__ out,
                     unsigned long long* __restrict__ gmask0,
                     int* __restrict__ gmaskT)
{
    cg::grid_group grid = cg::this_grid();
    const int b = blockIdx.x * 256 + threadIdx.x;

    // in-kernel workspace zeroing (replaces memset graph node)
    if (threadIdx.x == 0 && blockIdx.x == 0) {
        *gmask0 = 0ull;
        #pragma unroll
        for (int g = 0; g < NT; ++g) gmaskT[g] = 0;
    }

    const float4 xi  = x_init[b];   // [p1, p2, v1, v2]
    const float4 xdv = xd[b];
    const float SQ01 = 0.31622776601683794f;
    f2 xip = {xi.x, xi.y};
    f2 xiv = {xi.z, xi.w};
    f2 pcp = {-xdv.x, -xdv.y};
    f2 pcv = {-SQ01*xdv.z, -SQ01*xdv.w};

    // Batch-independent Riccati gain schedule (constant-folds at compile time)
    float c0[T_HOR], c1[T_HOR], gp[T_HOR], hp[T_HOR];
    {
        float Vpp = 0.f, Vpv = 0.f, Vvv = 0.f;
        #pragma unroll
        for (int t = T_HOR-1; t >= 0; --t) {
            float s  = 0.25f * Vvv;
            float tw = 0.1f + 2.f*s;
            float dd = 0.1f * tw;
            c0[t] = (0.1f + s) / dd;
            c1[t] = s / dd;
            float g = 0.5f * Vpv;
            float h = 0.05f * Vpv + 0.375f * Vvv;
            float inv = 1.f / tw;
            gp[t] = g * inv;
            hp[t] = h * inv;
            float nVpp = 1.0f + Vpp - 2.f*g*gp[t];
            float nVpv = 0.1f*Vpp + 0.75f*Vpv - 2.f*g*hp[t];
            float nVvv = 0.1f + 0.01f*Vpp + 0.15f*Vpv + 0.5625f*Vvv - 2.f*h*hp[t];
            Vpp = nVpp; Vpv = nVpv; Vvv = nVvv;
        }
    }

    f2 zero2 = {0.f, 0.f};
    f2 ua[T_HOR], ub[T_HOR];
    #pragma unroll
    for (int t = 0; t < T_HOR; ++t) { ua[t] = zero2; ub[t] = zero2; }

    grid.sync();   // workspace zeroing visible before any atomicOr

    float4 result;
    bool done = false;

    // ---- group 0: G0 iterations, 64-bit convergence mask
    unsigned long long mask = 0ull;
    for (int j = 0; j < G0; ++j) {
        float d = iter_once(c0, c1, gp, hp, xip, xiv, pcp, pcv, ua, ub);
        mask |= (unsigned long long)(d > EPSC ? 1u : 0u) << j;
    }
    int mlo = __syncthreads_or((int)(unsigned)mask);
    int mhi = __syncthreads_or((int)(unsigned)(mask >> 32));
    if (threadIdx.x == 0) {
        unsigned long long bm = ((unsigned long long)(unsigned)mhi << 32) | (unsigned)mlo;
        if (bm) __hip_atomic_fetch_or(gmask0, bm, __ATOMIC_RELEASE, __HIP_MEMORY_SCOPE_AGENT);
    }
    grid.sync();
    unsigned long long gm = __hip_atomic_load(gmask0, __ATOMIC_ACQUIRE, __HIP_MEMORY_SCOPE_AGENT);
    int j0 = (int)__builtin_ctzll(~gm);   // first iteration with global max<=EPS; <=G0 since bits>=G0 are 0
    if (j0 < G0) {
        // cold path (n* <= G0): replay j0+1 iterations from zeros
        #pragma unroll
        for (int t = 0; t < T_HOR; ++t) { ua[t] = zero2; ub[t] = zero2; }
        for (int j = 0; j <= j0; ++j)
            iter_once(c0, c1, gp, hp, xip, xiv, pcp, pcv, ua, ub);
        result = make_float4(ua[0].x, ub[0].x, ua[0].y, ub[0].y);
        done = true;
    }

    // ---- tail: groups of 4, record u[0] per iteration, select by first clear bit
    if (!done) {
        for (int g = 0; g < NT; ++g) {
            f2 r0[4], r1[4];
            unsigned msk = 0;
            #pragma unroll
            for (int j = 0; j < 4; ++j) {
                float d = iter_once(c0, c1, gp, hp, xip, xiv, pcp, pcv, ua, ub);
                r0[j] = ua[0]; r1[j] = ub[0];
                msk |= (d > EPSC ? 1u : 0u) << j;
            }
            int m = __syncthreads_or((int)msk);
            if (threadIdx.x == 0 && m) {
                __hip_atomic_fetch_or(&gmaskT[g], m, __ATOMIC_RELEASE, __HIP_MEMORY_SCOPE_AGENT);
            }
            grid.sync();
            int gmt = __hip_atomic_load(&gmaskT[g], __ATOMIC_ACQUIRE, __HIP_MEMORY_SCOPE_AGENT);
            int jj = (int)__builtin_ctz(~(unsigned)gmt);   // 0..4
            if (jj < 4) {
                f2 s0 = r0[0], s1 = r1[0];
                #pragma unroll
                for (int j = 1; j < 4; ++j) {
                    if (j == jj) { s0 = r0[j]; s1 = r1[j]; }
                }
                result = make_float4(s0.x, s1.x, s0.y, s1.y);
                done = true;
                break;
            }
        }
        if (!done) result = make_float4(ua[0].x, ub[0].x, ua[0].y, ub[0].y);
    }

    out[b] = result;
}

extern "C" void kernel_launch(void* const* d_in, const int* in_sizes, int n_in,
                              void* d_out, int out_size, void* d_ws, size_t ws_size,
                              hipStream_t stream) {
    const float4* x_init = (const float4*)d_in[0];
    const float4* xd     = (const float4*)d_in[1];
    float4* out          = (float4*)d_out;
    unsigned long long* gmask0 = (unsigned long long*)d_ws;
    int* gmaskT          = (int*)((char*)d_ws + 8);

    const int B = in_sizes[0] / 4;          // 65536
    void* args[] = { (void*)&x_init, (void*)&xd, (void*)&out, (void*)&gmask0, (void*)&gmaskT };
    dim3 grid(B / 256), block(256);
    hipLaunchCooperativeKernel((const void*)mpc_iter_kernel, grid, block, args, 0, stream);
}